// Round 1
// baseline (353.453 us; speedup 1.0000x reference)
//
#include <hip/hip_runtime.h>
#include <hip/hip_bf16.h>

// Problem: S=2048, B=32, H=1024
//   energies[s,b] = dot(hidden[b,:], enc[s,b,:])   (enc is [S,B,H] row-major)
//   out[b,0,s]    = softmax_over_s(energies)[s,b]
// HBM-bound: enc = 256 MB read once -> ~41 us floor at 6.3 TB/s.

#define SEQ_LEN 2048
#define BATCH   32
#define HIDDEN  1024

// One wave (64 lanes) per (s,b) pair. H elements are contiguous -> coalesced
// float4 loads: lane i reads float4 index lane + 64*k, k=0..3 (256 float4/row).
__global__ __launch_bounds__(256) void dot_kernel(
    const float* __restrict__ hidden,
    const float* __restrict__ enc,
    float* __restrict__ energies /* [B, S] */) {

    const int gtid    = blockIdx.x * blockDim.x + threadIdx.x;
    const int wave_id = gtid >> 6;            // = s*BATCH + b (matches enc row order)
    const int lane    = threadIdx.x & 63;

    const int s = wave_id / BATCH;
    const int b = wave_id - s * BATCH;

    const float4* __restrict__ row4 = (const float4*)(enc + (size_t)wave_id * HIDDEN);
    const float4* __restrict__ hid4 = (const float4*)(hidden + (size_t)b * HIDDEN);

    float acc = 0.0f;
#pragma unroll
    for (int k = 0; k < HIDDEN / 4 / 64; ++k) {   // 4 iterations
        const int i = lane + 64 * k;
        float4 a = row4[i];
        float4 c = hid4[i];
        acc += a.x * c.x + a.y * c.y + a.z * c.z + a.w * c.w;
    }

    // 64-lane butterfly reduce
#pragma unroll
    for (int off = 32; off > 0; off >>= 1)
        acc += __shfl_down(acc, off, 64);

    if (lane == 0)
        energies[b * SEQ_LEN + s] = acc;   // transposed store -> output layout
}

// One block per batch column: softmax over S=2048. 256 threads x 8 values each,
// register-resident; two block reductions (max, sum) through LDS.
__global__ __launch_bounds__(256) void softmax_kernel(
    const float* __restrict__ energies /* [B, S] */,
    float* __restrict__ out /* [B, 1, S] */) {

    const int b   = blockIdx.x;
    const int tid = threadIdx.x;
    const float* __restrict__ e = energies + (size_t)b * SEQ_LEN;
    float* __restrict__ o       = out      + (size_t)b * SEQ_LEN;

    float v[8];
    float m = -1e30f;
#pragma unroll
    for (int i = 0; i < 8; ++i) {
        v[i] = e[tid + i * 256];
        m = fmaxf(m, v[i]);
    }

    const int wave = tid >> 6, lane = tid & 63;
    __shared__ float smax[4];
    __shared__ float ssum[4];

#pragma unroll
    for (int off = 32; off > 0; off >>= 1)
        m = fmaxf(m, __shfl_down(m, off, 64));
    if (lane == 0) smax[wave] = m;
    __syncthreads();
    const float bm = fmaxf(fmaxf(smax[0], smax[1]), fmaxf(smax[2], smax[3]));

    float sum = 0.0f;
#pragma unroll
    for (int i = 0; i < 8; ++i) {
        v[i] = __expf(v[i] - bm);
        sum += v[i];
    }
#pragma unroll
    for (int off = 32; off > 0; off >>= 1)
        sum += __shfl_down(sum, off, 64);
    if (lane == 0) ssum[wave] = sum;
    __syncthreads();
    const float inv = 1.0f / (ssum[0] + ssum[1] + ssum[2] + ssum[3]);

#pragma unroll
    for (int i = 0; i < 8; ++i)
        o[tid + i * 256] = v[i] * inv;
}

extern "C" void kernel_launch(void* const* d_in, const int* in_sizes, int n_in,
                              void* d_out, int out_size, void* d_ws, size_t ws_size,
                              hipStream_t stream) {
    const float* hidden = (const float*)d_in[0];   // [B, H]
    const float* enc    = (const float*)d_in[1];   // [S, B, H]
    float* out          = (float*)d_out;           // [B, 1, S]
    float* energies     = (float*)d_ws;            // [B, S] = 256 KB scratch

    const int total_waves = SEQ_LEN * BATCH;               // 65536
    const int blocks      = total_waves / (256 / 64);      // 16384

    dot_kernel<<<blocks, 256, 0, stream>>>(hidden, enc, energies);
    softmax_kernel<<<BATCH, 256, 0, stream>>>(energies, out);
}